// Round 20
// baseline (499.662 us; speedup 1.0000x reference)
//
#include <hip/hip_runtime.h>

// VQ-VAE quantizer, MI355X (gfx950). Round 20:
//   proj v2: BM128xBN128 (grid 256x2, was 256x4) -> feat HBM traffic halved,
//     32 MFMA/kt/wave (2x ratio). Per-output chain bit-identical to r19.
//   argmin v8: codebook split x2 (grid 512x2, zero-LDS kept) -> 4 blocks/CU;
//     per-split top-2 -> tmp, exact merge kernel (r16 algebra) + TAU flag.
// prep/transpose/exact_rows/rescan/gather/loss identical to r19 (PASS).

typedef _Float16 f16;
typedef _Float16 half8 __attribute__((ext_vector_type(8)));
typedef float floatx4 __attribute__((ext_vector_type(4)));

#define ROWS   32768
#define IN_DIM 1024
#define DDIM   256
#define KEMB   4096
#define TAU    0.125f
#define RSB    8
#define ERB    8
#define NSPLIT 2
#define NTPER  16   // 32 nt-tiles / NSPLIT

__device__ __forceinline__ float fmul(float a, float b) { return __fmul_rn(a, b); }
__device__ __forceinline__ float fadd(float a, float b) { return __fadd_rn(a, b); }

__device__ __forceinline__ void split2(float x, f16& hi, f16& lo) {
    float h = (float)(f16)x;
    if (__builtin_fabsf(h) < 6.1035156e-5f) h = 0.0f;
    hi = (f16)h;
    lo = (f16)((x - h) * 2048.0f);
}

// np.sum(x*x) over 256 f32: pairwise 128+128; AVX512 vstep=16 block tree.
__device__ float np_sumsq_256(const float* __restrict__ x) {
    float blk[2];
    #pragma unroll
    for (int h = 0; h < 2; ++h) {
        const float* p = x + h * 128;
        float s[16];
        #pragma unroll
        for (int l = 0; l < 16; ++l) {
            float q0 = fmul(p[l],       p[l]);
            float q1 = fmul(p[16 + l],  p[16 + l]);
            float q2 = fmul(p[32 + l],  p[32 + l]);
            float q3 = fmul(p[48 + l],  p[48 + l]);
            float q4 = fmul(p[64 + l],  p[64 + l]);
            float q5 = fmul(p[80 + l],  p[80 + l]);
            float q6 = fmul(p[96 + l],  p[96 + l]);
            float q7 = fmul(p[112 + l], p[112 + l]);
            s[l] = fadd(fadd(fadd(q0, q1), fadd(q2, q3)),
                        fadd(fadd(q4, q5), fadd(q6, q7)));
        }
        float t1[8];
        #pragma unroll
        for (int l = 0; l < 8; ++l) t1[l] = fadd(s[l], s[l + 8]);
        float t2[4];
        #pragma unroll
        for (int l = 0; l < 4; ++l) t2[l] = fadd(t1[l], t1[l + 4]);
        blk[h] = fadd(fadd(t2[0], t2[2]), fadd(t2[1], t2[3]));
    }
    return fadd(blk[0], blk[1]);
}

// ---------------------------------------------------------------- K0: W transpose
__global__ __launch_bounds__(256) void vq_transpose_w(
    const float* __restrict__ Wm, float* __restrict__ WT)
{
    __shared__ float t[64][65];
    const int d0 = blockIdx.x * 64, k0 = blockIdx.y * 64;
    const int tid = threadIdx.x;
    for (int e = tid; e < 4096; e += 256) {
        int dr = e >> 6, kc = e & 63;
        t[dr][kc] = Wm[(size_t)(d0 + dr) * IN_DIM + k0 + kc];
    }
    __syncthreads();
    for (int e = tid; e < 4096; e += 256) {
        int kr = e >> 6, dc = e & 63;
        WT[(size_t)(k0 + kr) * DDIM + d0 + dc] = t[dc][kr];
    }
}

// ---------------------------------------------------------------- K1: prep (chiF + norms)
__global__ __launch_bounds__(256) void vq_prep_codebook(
    const float* __restrict__ cb, f16* __restrict__ chiF, float* __restrict__ cn3)
{
    int j = blockIdx.x;
    int d = threadIdx.x;
    float c = cb[(size_t)j * DDIM + d] * 4096.0f;
    f16 hi, lo;
    split2(c, hi, lo);
    chiF[((size_t)(j >> 4) * 32 + (d >> 3)) * 128 + (size_t)(j & 15) * 8 + (d & 7)] = hi;
    float sq = c * c;
    #pragma unroll
    for (int off = 32; off > 0; off >>= 1) sq += __shfl_down(sq, off);
    __shared__ float red[4];
    if ((threadIdx.x & 63) == 0) red[threadIdx.x >> 6] = sq;
    __syncthreads();
    if (threadIdx.x == 0)
        cn3[j] = (red[0] + red[1] + red[2] + red[3]) * (1.0f / 8192.0f);
}

// ---------------------------------------------------------------- K2: proj v2 (MFMA split-f16, BM128xBN128)
// 256 threads, 2x2 waves of 64x64 (mi,ni = 0..3). Per-output K-chain identical
// to r19 (same 32 BK=32 steps, same fragments, acc1 + acc2/2048 + bias).
__global__ __launch_bounds__(256) void vq_proj_mfma(
    const float* __restrict__ feat, const float* __restrict__ Wm,
    const float* __restrict__ bias, float* __restrict__ pf, f16* __restrict__ phi)
{
    __shared__ f16 FH[128][40], WH[128][40], WL[128][40];
    const int m0 = blockIdx.x * 128;
    const int n0 = blockIdx.y * 128;
    const int tid = threadIdx.x;
    const int lane = tid & 63;
    const int w = tid >> 6;
    const int wr = w >> 1, wc = w & 1;
    const int l15 = lane & 15;
    const int lhi = lane >> 4;

    floatx4 acc1[4][4], acc2[4][4];
    #pragma unroll
    for (int mi = 0; mi < 4; ++mi)
        #pragma unroll
        for (int ni = 0; ni < 4; ++ni) {
            acc1[mi][ni] = (floatx4){0.f, 0.f, 0.f, 0.f};
            acc2[mi][ni] = (floatx4){0.f, 0.f, 0.f, 0.f};
        }

    for (int kt = 0; kt < IN_DIM / 32; ++kt) {
        { // stage feat tile [128][32] -> f16 hi (16 floats/thread)
            int r = tid >> 1, h = (tid & 1) * 16;
            const float* src = feat + (size_t)(m0 + r) * IN_DIM + kt * 32 + h;
            f16 th[16];
            #pragma unroll
            for (int i = 0; i < 16; i += 4) {
                float4 v = *(const float4*)(src + i);
                th[i+0] = (f16)v.x;
                th[i+1] = (f16)v.y;
                th[i+2] = (f16)v.z;
                th[i+3] = (f16)v.w;
            }
            *(half8*)&FH[r][h]     = *(half8*)&th[0];
            *(half8*)&FH[r][h + 8] = *(half8*)&th[8];
        }
        { // stage W tile [128][32] -> hi/lo split (16 floats/thread)
            int c = tid >> 1, q = (tid & 1) * 16;
            const float* src = Wm + (size_t)(n0 + c) * IN_DIM + kt * 32 + q;
            f16 th[16], tl[16];
            #pragma unroll
            for (int i = 0; i < 16; i += 4) {
                float4 v = *(const float4*)(src + i);
                split2(v.x, th[i+0], tl[i+0]);
                split2(v.y, th[i+1], tl[i+1]);
                split2(v.z, th[i+2], tl[i+2]);
                split2(v.w, th[i+3], tl[i+3]);
            }
            *(half8*)&WH[c][q]     = *(half8*)&th[0];
            *(half8*)&WH[c][q + 8] = *(half8*)&th[8];
            *(half8*)&WL[c][q]     = *(half8*)&tl[0];
            *(half8*)&WL[c][q + 8] = *(half8*)&tl[8];
        }
        __syncthreads();

        const int k8 = lhi * 8;
        half8 aH[4], bH[4], bL[4];
        #pragma unroll
        for (int mi = 0; mi < 4; ++mi) {
            int r = wr * 64 + mi * 16 + l15;
            aH[mi] = *(half8*)&FH[r][k8];
        }
        #pragma unroll
        for (int ni = 0; ni < 4; ++ni) {
            int c = wc * 64 + ni * 16 + l15;
            bH[ni] = *(half8*)&WH[c][k8];
            bL[ni] = *(half8*)&WL[c][k8];
        }
        #pragma unroll
        for (int mi = 0; mi < 4; ++mi)
            #pragma unroll
            for (int ni = 0; ni < 4; ++ni) {
                acc1[mi][ni] = __builtin_amdgcn_mfma_f32_16x16x32_f16(aH[mi], bH[ni], acc1[mi][ni], 0, 0, 0);
                acc2[mi][ni] = __builtin_amdgcn_mfma_f32_16x16x32_f16(aH[mi], bL[ni], acc2[mi][ni], 0, 0, 0);
            }
        __syncthreads();
    }

    #pragma unroll
    for (int ni = 0; ni < 4; ++ni) {
        int col = n0 + wc * 64 + ni * 16 + l15;
        float bv = bias[col];
        #pragma unroll
        for (int mi = 0; mi < 4; ++mi) {
            #pragma unroll
            for (int j = 0; j < 4; ++j) {
                int row = m0 + wr * 64 + mi * 16 + lhi * 4 + j;
                float p = acc1[mi][ni][j] + acc2[mi][ni][j] * (1.0f / 2048.0f) + bv;
                pf[(size_t)row * DDIM + col] = p;
                f16 hi, dead;
                split2(p, hi, dead);
                phi[(size_t)row * DDIM + col] = hi;
            }
        }
    }
}

// ---------------------------------------------------------------- K3: MFMA argmin filter (v8, split x2)
// blockIdx.y = codebook split (16 nt-tiles). Zero-LDS; score = dot - cn;
// max-tree top-2. Per-split results to tmp; merge kernel combines + flags.
__global__ __launch_bounds__(256) void vq_argmin(
    const f16* __restrict__ phi,
    const f16* __restrict__ chiF,
    const float* __restrict__ cn3,
    float* __restrict__ tV1, float* __restrict__ tV2, int* __restrict__ tI1)
{
    __shared__ float mV1[64][2], mV2[64][2];
    __shared__ int   mI1[64][2];
    const int m0 = blockIdx.x * 64;
    const int split = blockIdx.y;
    const int tid = threadIdx.x;
    const int lane = tid & 63;
    const int w = tid >> 6;
    const int wr = w >> 1, wc = w & 1;
    const int l15 = lane & 15;
    const int lhi = lane >> 4;

    half8 aH[2][8];
    #pragma unroll
    for (int mi = 0; mi < 2; ++mi) {
        const int row = m0 + wr * 32 + mi * 16 + l15;
        #pragma unroll
        for (int t = 0; t < 8; ++t)
            aH[mi][t] = *(const half8*)&phi[(size_t)row * DDIM + t * 32 + lhi * 8];
    }

    float v1s[8], v2s[8];
    int i1s[8];
    #pragma unroll
    for (int s = 0; s < 8; ++s) { v1s[s] = -__builtin_inff(); v2s[s] = -__builtin_inff(); i1s[s] = 0; }

    const int nt0 = split * NTPER;
    for (int nt = nt0; nt < nt0 + NTPER; ++nt) {
        floatx4 acc1[2][4];
        #pragma unroll
        for (int mi = 0; mi < 2; ++mi)
            #pragma unroll
            for (int ni = 0; ni < 4; ++ni)
                acc1[mi][ni] = (floatx4){0.f, 0.f, 0.f, 0.f};

        #pragma unroll
        for (int ks = 0; ks < 4; ++ks) {
            #pragma unroll
            for (int kb = 0; kb < 2; ++kb) {
                const int t = ks * 8 + kb * 4 + lhi;
                half8 bH[4];
                #pragma unroll
                for (int ni = 0; ni < 4; ++ni) {
                    const int c16 = nt * 8 + wc * 4 + ni;
                    bH[ni] = *(const half8*)&chiF[((size_t)c16 * 32 + t) * 128 + (size_t)l15 * 8];
                }
                #pragma unroll
                for (int mi = 0; mi < 2; ++mi)
                    #pragma unroll
                    for (int ni = 0; ni < 4; ++ni)
                        acc1[mi][ni] = __builtin_amdgcn_mfma_f32_16x16x32_f16(aH[mi][ks * 2 + kb], bH[ni], acc1[mi][ni], 0, 0, 0);
            }
        }

        const int colbase = nt * 128 + wc * 64 + l15;
        float cn0 = cn3[colbase];
        float cn1 = cn3[colbase + 16];
        float cn2 = cn3[colbase + 32];
        float cn3v = cn3[colbase + 48];
        #pragma unroll
        for (int mi = 0; mi < 2; ++mi)
            #pragma unroll
            for (int j = 0; j < 4; ++j) {
                const int s = mi * 4 + j;
                float x0 = acc1[mi][0][j] - cn0;
                float x1 = acc1[mi][1][j] - cn1;
                float x2 = acc1[mi][2][j] - cn2;
                float x3 = acc1[mi][3][j] - cn3v;
                float mx = fmaxf(fmaxf(x0, x1), fmaxf(x2, x3));
                if (mx > v1s[s]) {
                    int nidx; float rest;
                    if (x0 == mx)      { nidx = 0; rest = fmaxf(fmaxf(x1, x2), x3); }
                    else if (x1 == mx) { nidx = 1; rest = fmaxf(fmaxf(x0, x2), x3); }
                    else if (x2 == mx) { nidx = 2; rest = fmaxf(fmaxf(x0, x1), x3); }
                    else               { nidx = 3; rest = fmaxf(fmaxf(x0, x1), x2); }
                    v2s[s] = fmaxf(v1s[s], rest);
                    v1s[s] = mx;
                    i1s[s] = colbase + nidx * 16;
                } else {
                    v2s[s] = fmaxf(v2s[s], mx);
                }
            }
    }

    #pragma unroll
    for (int s = 0; s < 8; ++s) {
        float a1 = v1s[s], a2 = v2s[s];
        int ai = i1s[s];
        #pragma unroll
        for (int m = 1; m < 16; m <<= 1) {
            float b1 = __shfl_xor(a1, m);
            float b2 = __shfl_xor(a2, m);
            int   bi = __shfl_xor(ai, m);
            float n2 = fmaxf(fminf(a1, b1), fmaxf(a2, b2));
            if (b1 > a1 || (b1 == a1 && bi < ai)) { a1 = b1; ai = bi; }
            a2 = n2;
        }
        v1s[s] = a1; v2s[s] = a2; i1s[s] = ai;
    }
    if (l15 == 0) {
        #pragma unroll
        for (int s = 0; s < 8; ++s) {
            int mi = s >> 2, j = s & 3;
            int rloc = wr * 32 + mi * 16 + lhi * 4 + j;
            mV1[rloc][wc] = v1s[s]; mV2[rloc][wc] = v2s[s];
            mI1[rloc][wc] = i1s[s];
        }
    }
    __syncthreads();
    if (tid < 64) {
        float a1 = mV1[tid][0], a2 = mV2[tid][0], b1 = mV1[tid][1], b2 = mV2[tid][1];
        int ai = mI1[tid][0], bi = mI1[tid][1];
        float n2 = fmaxf(fminf(a1, b1), fmaxf(a2, b2));
        if (b1 > a1 || (b1 == a1 && bi < ai)) { a1 = b1; ai = bi; }
        size_t o = (size_t)split * ROWS + m0 + tid;
        tV1[o] = a1; tV2[o] = n2; tI1[o] = ai;
    }
}

// ---------------------------------------------------------------- K3m: merge splits + flag
__global__ __launch_bounds__(256) void vq_merge(
    const float* __restrict__ tV1, const float* __restrict__ tV2,
    const int* __restrict__ tI1, int* __restrict__ out_idx,
    int* __restrict__ fs_cnt, int* __restrict__ fs_list)
{
    const int row = blockIdx.x * 256 + threadIdx.x;
    float a1 = tV1[row], a2 = tV2[row];
    int ai = tI1[row];
    #pragma unroll
    for (int s = 1; s < NSPLIT; ++s) {
        size_t o = (size_t)s * ROWS + row;
        float b1 = tV1[o], b2 = tV2[o];
        int bi = tI1[o];
        if (b1 > a1 || (b1 == a1 && bi < ai)) {
            a2 = fmaxf(a1, b2);
            a1 = b1; ai = bi;
        } else {
            a2 = fmaxf(a2, b1);
        }
    }
    out_idx[row] = ai;
    if (a1 - a2 < TAU) {
        int slot = atomicAdd(fs_cnt, 1);
        fs_list[slot] = row;
    }
}

// ---------------------------------------------------------------- K3b: cb transpose (f32)
__global__ __launch_bounds__(256) void vq_transpose_cb(
    const float* __restrict__ cb, float* __restrict__ cbT)
{
    __shared__ float t[64][65];
    const int j0 = blockIdx.x * 64, d0 = blockIdx.y * 64;
    const int tid = threadIdx.x;
    for (int e = tid; e < 4096; e += 256) {
        int jr = e >> 6, dc = e & 63;
        t[jr][dc] = cb[(size_t)(j0 + jr) * DDIM + d0 + dc];
    }
    __syncthreads();
    for (int e = tid; e < 4096; e += 256) {
        int dr = e >> 6, jc = e & 63;
        cbT[(size_t)(d0 + dr) * KEMB + j0 + jc] = t[jc][dr];
    }
}

// ---------------------------------------------------------------- K3c: np-exact proj for flagged rows (v2)
__global__ __launch_bounds__(256) void vq_proj_exact_rows(
    const float* __restrict__ feat, const float* __restrict__ WT,
    const float* __restrict__ bias, const int* __restrict__ fs_list,
    const int* __restrict__ fs_cnt, float* __restrict__ pf)
{
    const int d = threadIdx.x;
    int cnt = *fs_cnt;
    if (cnt > ROWS) cnt = ROWS;
    for (int base = blockIdx.x * ERB; base < cnt; base += gridDim.x * ERB) {
        const int nr = min(ERB, cnt - base);
        int rows[ERB];
        #pragma unroll
        for (int r = 0; r < ERB; ++r)
            rows[r] = fs_list[base + ((r < nr) ? r : (nr - 1))];

        float acc[ERB][4];
        #pragma unroll
        for (int r = 0; r < ERB; ++r)
            #pragma unroll
            for (int l = 0; l < 4; ++l)
                acc[r][l] = 0.0f;

        #pragma unroll 1
        for (int ch = 0; ch < IN_DIM / 16; ++ch) {
            const int ko = ch * 16;
            float wk[16];
            #pragma unroll
            for (int k = 0; k < 16; ++k)
                wk[k] = WT[(size_t)(ko + k) * DDIM + d];
            #pragma unroll
            for (int r = 0; r < ERB; ++r) {
                const float* fr = feat + (size_t)rows[r] * IN_DIM + ko;  // uniform
                float4 f3 = *(const float4*)(fr + 12);
                float4 f2 = *(const float4*)(fr + 8);
                float4 f1 = *(const float4*)(fr + 4);
                float4 f0 = *(const float4*)(fr);
                acc[r][0] = fadd(acc[r][0], fmul(f3.x, wk[12]));
                acc[r][1] = fadd(acc[r][1], fmul(f3.y, wk[13]));
                acc[r][2] = fadd(acc[r][2], fmul(f3.z, wk[14]));
                acc[r][3] = fadd(acc[r][3], fmul(f3.w, wk[15]));
                acc[r][0] = fadd(acc[r][0], fmul(f2.x, wk[8]));
                acc[r][1] = fadd(acc[r][1], fmul(f2.y, wk[9]));
                acc[r][2] = fadd(acc[r][2], fmul(f2.z, wk[10]));
                acc[r][3] = fadd(acc[r][3], fmul(f2.w, wk[11]));
                acc[r][0] = fadd(acc[r][0], fmul(f1.x, wk[4]));
                acc[r][1] = fadd(acc[r][1], fmul(f1.y, wk[5]));
                acc[r][2] = fadd(acc[r][2], fmul(f1.z, wk[6]));
                acc[r][3] = fadd(acc[r][3], fmul(f1.w, wk[7]));
                acc[r][0] = fadd(acc[r][0], fmul(f0.x, wk[0]));
                acc[r][1] = fadd(acc[r][1], fmul(f0.y, wk[1]));
                acc[r][2] = fadd(acc[r][2], fmul(f0.z, wk[2]));
                acc[r][3] = fadd(acc[r][3], fmul(f0.w, wk[3]));
            }
        }

        const float bv = bias[d];
        for (int r = 0; r < nr; ++r) {
            float h = fadd(fadd(acc[r][0], acc[r][1]), fadd(acc[r][2], acc[r][3]));
            pf[(size_t)rows[r] * DDIM + d] = fadd(h, bv);
        }
    }
}

// ---------------------------------------------------------------- K4: np-exact rescan (reg-blocked)
__global__ __launch_bounds__(256) void vq_np_rescan(
    const float* __restrict__ pf, const float* __restrict__ cbT,
    const int* __restrict__ fs_list, const int* __restrict__ fs_cnt,
    int* __restrict__ out_idx)
{
    __shared__ float prow[RSB][DDIM];
    __shared__ float As[RSB];
    __shared__ float rD[RSB][4];
    __shared__ int   rJ[RSB][4];
    const int tid = threadIdx.x;
    const int lane = tid & 63;
    const int wv = tid >> 6;
    int cnt = *fs_cnt;
    if (cnt > ROWS) cnt = ROWS;

    for (int base = blockIdx.x * RSB; base < cnt; base += gridDim.x * RSB) {
        const int nr = min(RSB, cnt - base);
        __syncthreads();
        for (int i = tid; i < nr * 64; i += 256) {
            int r = i >> 6, q = (i & 63) * 4;
            *(float4*)&prow[r][q] =
                *(const float4*)&pf[(size_t)fs_list[base + r] * DDIM + q];
        }
        __syncthreads();
        if (tid < nr) As[tid] = np_sumsq_256(prow[tid]);
        __syncthreads();

        float bD[RSB]; int bJ[RSB];
        #pragma unroll
        for (int r = 0; r < RSB; ++r) { bD[r] = __builtin_inff(); bJ[r] = 0x7fffffff; }

        for (int sw = 0; sw < 4; ++sw) {
            const int j0 = sw * 1024 + tid * 4;
            float4 acc[RSB];
            #pragma unroll
            for (int r = 0; r < RSB; ++r) acc[r] = (float4){0.f, 0.f, 0.f, 0.f};
            for (int d4 = 0; d4 < DDIM / 4; ++d4) {
                float4 pv[RSB];
                #pragma unroll
                for (int r = 0; r < RSB; ++r)
                    pv[r] = *(const float4*)&prow[r][d4 * 4];
                #pragma unroll
                for (int dd = 0; dd < 4; ++dd) {
                    float4 cv = *(const float4*)&cbT[(size_t)(d4 * 4 + dd) * KEMB + j0];
                    #pragma unroll
                    for (int r = 0; r < RSB; ++r) {
                        float p = (dd == 0) ? pv[r].x : (dd == 1) ? pv[r].y
                                 : (dd == 2) ? pv[r].z : pv[r].w;
                        acc[r].x = __fmaf_rn(p, cv.x, acc[r].x);
                        acc[r].y = __fmaf_rn(p, cv.y, acc[r].y);
                        acc[r].z = __fmaf_rn(p, cv.z, acc[r].z);
                        acc[r].w = __fmaf_rn(p, cv.w, acc[r].w);
                    }
                }
            }
            #pragma unroll
            for (int r = 0; r < RSB; ++r) {
                float A = As[r];
                float D0 = fadd(A, fmul(-2.0f, acc[r].x));
                float D1 = fadd(A, fmul(-2.0f, acc[r].y));
                float D2 = fadd(A, fmul(-2.0f, acc[r].z));
                float D3 = fadd(A, fmul(-2.0f, acc[r].w));
                if (D0 < bD[r]) { bD[r] = D0; bJ[r] = j0; }
                if (D1 < bD[r]) { bD[r] = D1; bJ[r] = j0 + 1; }
                if (D2 < bD[r]) { bD[r] = D2; bJ[r] = j0 + 2; }
                if (D3 < bD[r]) { bD[r] = D3; bJ[r] = j0 + 3; }
            }
        }

        #pragma unroll
        for (int r = 0; r < RSB; ++r) {
            float d_ = bD[r]; int j_ = bJ[r];
            #pragma unroll
            for (int m = 1; m < 64; m <<= 1) {
                float od = __shfl_xor(d_, m);
                int   oj = __shfl_xor(j_, m);
                if (od < d_ || (od == d_ && oj < j_)) { d_ = od; j_ = oj; }
            }
            if (lane == 0) { rD[r][wv] = d_; rJ[r][wv] = j_; }
        }
        __syncthreads();
        if (tid < nr) {
            float d_ = rD[tid][0]; int j_ = rJ[tid][0];
            #pragma unroll
            for (int q = 1; q < 4; ++q) {
                float od = rD[tid][q]; int oj = rJ[tid][q];
                if (od < d_ || (od == d_ && oj < j_)) { d_ = od; j_ = oj; }
            }
            out_idx[fs_list[base + tid]] = j_;
        }
    }
}

// ---------------------------------------------------------------- K5: gather + loss partials
__global__ __launch_bounds__(256) void vq_gather(
    const float* __restrict__ cb, const float* __restrict__ pf,
    const int* __restrict__ idx,
    float* __restrict__ out0, float* __restrict__ outIdxF,
    float* __restrict__ partials)
{
    const int tid = threadIdx.x;
    const int lane = tid & 63;
    const int w = tid >> 6;
    const int row = blockIdx.x * 4 + w;
    const int k = idx[row];

    float4 c = *(const float4*)&cb[(size_t)k * DDIM + lane * 4];
    float4 p = *(const float4*)&pf[(size_t)row * DDIM + lane * 4];
    float d0 = c.x - p.x, d1 = c.y - p.y, d2 = c.z - p.z, d3 = c.w - p.w;
    float s = d0 * d0 + d1 * d1 + d2 * d2 + d3 * d3;

    *(float4*)&out0[(size_t)row * DDIM + lane * 4] = c;
    if (lane == 0) outIdxF[row] = (float)k;

    #pragma unroll
    for (int off = 32; off > 0; off >>= 1) s += __shfl_down(s, off);
    __shared__ float red[4];
    if (lane == 0) red[w] = s;
    __syncthreads();
    if (tid == 0) partials[blockIdx.x] = red[0] + red[1] + red[2] + red[3];
}

// ---------------------------------------------------------------- K6: loss reduce
__global__ __launch_bounds__(256) void vq_loss(
    const float* __restrict__ partials, float* __restrict__ out_loss)
{
    const int tid = threadIdx.x;
    float s = 0.f;
    for (int i = tid; i < ROWS / 4; i += 256) s += partials[i];
    #pragma unroll
    for (int off = 32; off > 0; off >>= 1) s += __shfl_down(s, off);
    __shared__ float red[4];
    if ((tid & 63) == 0) red[tid >> 6] = s;
    __syncthreads();
    if (tid == 0)
        out_loss[0] = 1.25f * (red[0] + red[1] + red[2] + red[3]) / 8388608.0f;
}

// ---------------------------------------------------------------- launch
extern "C" void kernel_launch(void* const* d_in, const int* in_sizes, int n_in,
                              void* d_out, int out_size, void* d_ws, size_t ws_size,
                              hipStream_t stream) {
    const float* feat = (const float*)d_in[0];
    const float* Wm   = (const float*)d_in[1];
    const float* bias = (const float*)d_in[2];
    const float* cb   = (const float*)d_in[3];

    char* ws = (char*)d_ws;
    float* pf       = (float*)(ws);               // 32 MiB
    f16*   chiF     = (f16*)(ws + 33554432);      // 2 MiB  } chiF dead after argmin
    float* cbT      = (float*)(ws + 33554432);    // 4 MiB  } cbT overlays (after merge)
    float* tV1      = (float*)(ws + 35651584);    // 256 KiB } in cbT upper half:
    float* tV2      = (float*)(ws + 35913728);    // 256 KiB } dead after merge,
    int*   tI1      = (int*)(ws + 36175872);      // 256 KiB } before transpose_cb
    float* cn3      = (float*)(ws + 37748736);    // 16 KiB
    int*   idx      = (int*)(ws + 37765120);      // 128 KiB
    float* partials = (float*)(ws + 37896192);    // 32 KiB
    int*   fs_cnt   = (int*)(ws + 37928960);      // 128 B
    int*   fs_list  = (int*)(ws + 37929088);      // 128 KiB (ends 38060160)
    float* WT       = (float*)(ws + 38076416);    // 1 MiB f32 [1024][256]
    f16*   phi      = (f16*)(ws + 39124992);      // 16 MiB f16 [32768][256]

    float* out0    = (float*)d_out;
    float* outLoss = (float*)d_out + 8388608;
    float* outIdxF = (float*)d_out + 8388609;

    hipMemsetAsync(fs_cnt, 0, 4, stream);
    vq_transpose_w<<<dim3(DDIM / 64, IN_DIM / 64), 256, 0, stream>>>(Wm, WT);
    vq_prep_codebook<<<KEMB, 256, 0, stream>>>(cb, chiF, cn3);
    vq_proj_mfma<<<dim3(ROWS / 128, DDIM / 128), 256, 0, stream>>>(feat, Wm, bias, pf, phi);
    vq_argmin<<<dim3(ROWS / 64, NSPLIT), 256, 0, stream>>>(phi, chiF, cn3, tV1, tV2, tI1);
    vq_merge<<<ROWS / 256, 256, 0, stream>>>(tV1, tV2, tI1, idx, fs_cnt, fs_list);
    vq_transpose_cb<<<dim3(KEMB / 64, DDIM / 64), 256, 0, stream>>>(cb, cbT);
    vq_proj_exact_rows<<<256, 256, 0, stream>>>(feat, WT, bias, fs_list, fs_cnt, pf);
    vq_np_rescan<<<512, 256, 0, stream>>>(pf, cbT, fs_list, fs_cnt, idx);
    vq_gather<<<ROWS / 4, 256, 0, stream>>>(cb, pf, idx, out0, outIdxF, partials);
    vq_loss<<<1, 256, 0, stream>>>(partials, outLoss);
}

// Round 21
// 439.976 us; speedup vs baseline: 1.1357x; 1.1357x over previous
//
#include <hip/hip_runtime.h>

// VQ-VAE quantizer, MI355X (gfx950). Round 21: REVERT to round-19 config
// (measured 440us — best). r20's proj BN128 + argmin split x2 both regressed
// (occupancy stayed 22%, extra P reloads + LDS footprint). This is r19 verbatim:
//   argmin v7b: zero-LDS, score = dot - cn, max-tree top-2, no split (134us)
//   proj: MFMA split-f16 BM128xBN64 + phi epilogue
//   exact_rows v2 (8 rows/iter, W-chunk reuse), np-exact rescan, gather, loss.

typedef _Float16 f16;
typedef _Float16 half8 __attribute__((ext_vector_type(8)));
typedef float floatx4 __attribute__((ext_vector_type(4)));

#define ROWS   32768
#define IN_DIM 1024
#define DDIM   256
#define KEMB   4096
#define TAU    0.125f
#define RSB    8
#define ERB    8

__device__ __forceinline__ float fmul(float a, float b) { return __fmul_rn(a, b); }
__device__ __forceinline__ float fadd(float a, float b) { return __fadd_rn(a, b); }

__device__ __forceinline__ void split2(float x, f16& hi, f16& lo) {
    float h = (float)(f16)x;
    if (__builtin_fabsf(h) < 6.1035156e-5f) h = 0.0f;
    hi = (f16)h;
    lo = (f16)((x - h) * 2048.0f);
}

// np.sum(x*x) over 256 f32: pairwise 128+128; AVX512 vstep=16 block tree.
__device__ float np_sumsq_256(const float* __restrict__ x) {
    float blk[2];
    #pragma unroll
    for (int h = 0; h < 2; ++h) {
        const float* p = x + h * 128;
        float s[16];
        #pragma unroll
        for (int l = 0; l < 16; ++l) {
            float q0 = fmul(p[l],       p[l]);
            float q1 = fmul(p[16 + l],  p[16 + l]);
            float q2 = fmul(p[32 + l],  p[32 + l]);
            float q3 = fmul(p[48 + l],  p[48 + l]);
            float q4 = fmul(p[64 + l],  p[64 + l]);
            float q5 = fmul(p[80 + l],  p[80 + l]);
            float q6 = fmul(p[96 + l],  p[96 + l]);
            float q7 = fmul(p[112 + l], p[112 + l]);
            s[l] = fadd(fadd(fadd(q0, q1), fadd(q2, q3)),
                        fadd(fadd(q4, q5), fadd(q6, q7)));
        }
        float t1[8];
        #pragma unroll
        for (int l = 0; l < 8; ++l) t1[l] = fadd(s[l], s[l + 8]);
        float t2[4];
        #pragma unroll
        for (int l = 0; l < 4; ++l) t2[l] = fadd(t1[l], t1[l + 4]);
        blk[h] = fadd(fadd(t2[0], t2[2]), fadd(t2[1], t2[3]));
    }
    return fadd(blk[0], blk[1]);
}

// ---------------------------------------------------------------- K0: W transpose
__global__ __launch_bounds__(256) void vq_transpose_w(
    const float* __restrict__ Wm, float* __restrict__ WT)
{
    __shared__ float t[64][65];
    const int d0 = blockIdx.x * 64, k0 = blockIdx.y * 64;
    const int tid = threadIdx.x;
    for (int e = tid; e < 4096; e += 256) {
        int dr = e >> 6, kc = e & 63;
        t[dr][kc] = Wm[(size_t)(d0 + dr) * IN_DIM + k0 + kc];
    }
    __syncthreads();
    for (int e = tid; e < 4096; e += 256) {
        int kr = e >> 6, dc = e & 63;
        WT[(size_t)(k0 + kr) * DDIM + d0 + dc] = t[dc][kr];
    }
}

// ---------------------------------------------------------------- K1: prep (chiF + norms)
__global__ __launch_bounds__(256) void vq_prep_codebook(
    const float* __restrict__ cb, f16* __restrict__ chiF, float* __restrict__ cn3)
{
    int j = blockIdx.x;
    int d = threadIdx.x;
    float c = cb[(size_t)j * DDIM + d] * 4096.0f;
    f16 hi, lo;
    split2(c, hi, lo);
    chiF[((size_t)(j >> 4) * 32 + (d >> 3)) * 128 + (size_t)(j & 15) * 8 + (d & 7)] = hi;
    float sq = c * c;
    #pragma unroll
    for (int off = 32; off > 0; off >>= 1) sq += __shfl_down(sq, off);
    __shared__ float red[4];
    if ((threadIdx.x & 63) == 0) red[threadIdx.x >> 6] = sq;
    __syncthreads();
    if (threadIdx.x == 0)
        cn3[j] = (red[0] + red[1] + red[2] + red[3]) * (1.0f / 8192.0f);
}

// ---------------------------------------------------------------- K2: proj (MFMA split-f16, 2-pass on W)
__global__ __launch_bounds__(256) void vq_proj_mfma(
    const float* __restrict__ feat, const float* __restrict__ Wm,
    const float* __restrict__ bias, float* __restrict__ pf, f16* __restrict__ phi)
{
    __shared__ f16 FH[128][40], WH[64][40], WL[64][40];
    const int m0 = blockIdx.x * 128;
    const int n0 = blockIdx.y * 64;
    const int tid = threadIdx.x;
    const int lane = tid & 63;
    const int w = tid >> 6;
    const int wr = w >> 1, wc = w & 1;

    floatx4 acc1[4][2], acc2[4][2];
    #pragma unroll
    for (int mi = 0; mi < 4; ++mi)
        #pragma unroll
        for (int ni = 0; ni < 2; ++ni) {
            acc1[mi][ni] = (floatx4){0.f, 0.f, 0.f, 0.f};
            acc2[mi][ni] = (floatx4){0.f, 0.f, 0.f, 0.f};
        }

    for (int kt = 0; kt < IN_DIM / 32; ++kt) {
        {
            int r = tid >> 1, h = (tid & 1) * 16;
            const float* src = feat + (size_t)(m0 + r) * IN_DIM + kt * 32 + h;
            f16 th[16];
            #pragma unroll
            for (int i = 0; i < 16; i += 4) {
                float4 v = *(const float4*)(src + i);
                th[i+0] = (f16)v.x;
                th[i+1] = (f16)v.y;
                th[i+2] = (f16)v.z;
                th[i+3] = (f16)v.w;
            }
            *(half8*)&FH[r][h]     = *(half8*)&th[0];
            *(half8*)&FH[r][h + 8] = *(half8*)&th[8];
        }
        {
            int c = tid >> 2, q = (tid & 3) * 8;
            const float* src = Wm + (size_t)(n0 + c) * IN_DIM + kt * 32 + q;
            f16 th[8], tl[8];
            #pragma unroll
            for (int i = 0; i < 8; i += 4) {
                float4 v = *(const float4*)(src + i);
                split2(v.x, th[i+0], tl[i+0]);
                split2(v.y, th[i+1], tl[i+1]);
                split2(v.z, th[i+2], tl[i+2]);
                split2(v.w, th[i+3], tl[i+3]);
            }
            *(half8*)&WH[c][q] = *(half8*)&th[0];
            *(half8*)&WL[c][q] = *(half8*)&tl[0];
        }
        __syncthreads();

        const int k8 = (lane >> 4) * 8;
        const int l15 = lane & 15;
        half8 aH[4], bH[2], bL[2];
        #pragma unroll
        for (int mi = 0; mi < 4; ++mi) {
            int r = wr * 64 + mi * 16 + l15;
            aH[mi] = *(half8*)&FH[r][k8];
        }
        #pragma unroll
        for (int ni = 0; ni < 2; ++ni) {
            int c = wc * 32 + ni * 16 + l15;
            bH[ni] = *(half8*)&WH[c][k8];
            bL[ni] = *(half8*)&WL[c][k8];
        }
        #pragma unroll
        for (int mi = 0; mi < 4; ++mi)
            #pragma unroll
            for (int ni = 0; ni < 2; ++ni) {
                acc1[mi][ni] = __builtin_amdgcn_mfma_f32_16x16x32_f16(aH[mi], bH[ni], acc1[mi][ni], 0, 0, 0);
                acc2[mi][ni] = __builtin_amdgcn_mfma_f32_16x16x32_f16(aH[mi], bL[ni], acc2[mi][ni], 0, 0, 0);
            }
        __syncthreads();
    }

    #pragma unroll
    for (int ni = 0; ni < 2; ++ni) {
        int col = n0 + wc * 32 + ni * 16 + (lane & 15);
        float bv = bias[col];
        #pragma unroll
        for (int mi = 0; mi < 4; ++mi) {
            #pragma unroll
            for (int j = 0; j < 4; ++j) {
                int row = m0 + wr * 64 + mi * 16 + (lane >> 4) * 4 + j;
                float p = acc1[mi][ni][j] + acc2[mi][ni][j] * (1.0f / 2048.0f) + bv;
                pf[(size_t)row * DDIM + col] = p;
                f16 hi, dead;
                split2(p, hi, dead);
                phi[(size_t)row * DDIM + col] = hi;
            }
        }
    }
}

// ---------------------------------------------------------------- K3: MFMA argmin filter (v7b)
__global__ __launch_bounds__(256) void vq_argmin(
    const f16* __restrict__ phi,
    const f16* __restrict__ chiF,
    const float* __restrict__ cn3,
    int* __restrict__ out_idx,
    int* __restrict__ fs_cnt, int* __restrict__ fs_list)
{
    __shared__ float mV1[64][2], mV2[64][2];
    __shared__ int   mI1[64][2];
    const int m0 = blockIdx.x * 64;
    const int tid = threadIdx.x;
    const int lane = tid & 63;
    const int w = tid >> 6;
    const int wr = w >> 1, wc = w & 1;
    const int l15 = lane & 15;
    const int lhi = lane >> 4;

    half8 aH[2][8];
    #pragma unroll
    for (int mi = 0; mi < 2; ++mi) {
        const int row = m0 + wr * 32 + mi * 16 + l15;
        #pragma unroll
        for (int t = 0; t < 8; ++t)
            aH[mi][t] = *(const half8*)&phi[(size_t)row * DDIM + t * 32 + lhi * 8];
    }

    float v1s[8], v2s[8];
    int i1s[8];
    #pragma unroll
    for (int s = 0; s < 8; ++s) { v1s[s] = -__builtin_inff(); v2s[s] = -__builtin_inff(); i1s[s] = 0; }

    for (int nt = 0; nt < KEMB / 128; ++nt) {
        floatx4 acc1[2][4];
        #pragma unroll
        for (int mi = 0; mi < 2; ++mi)
            #pragma unroll
            for (int ni = 0; ni < 4; ++ni)
                acc1[mi][ni] = (floatx4){0.f, 0.f, 0.f, 0.f};

        #pragma unroll
        for (int ks = 0; ks < 4; ++ks) {
            #pragma unroll
            for (int kb = 0; kb < 2; ++kb) {
                const int t = ks * 8 + kb * 4 + lhi;
                half8 bH[4];
                #pragma unroll
                for (int ni = 0; ni < 4; ++ni) {
                    const int c16 = nt * 8 + wc * 4 + ni;
                    bH[ni] = *(const half8*)&chiF[((size_t)c16 * 32 + t) * 128 + (size_t)l15 * 8];
                }
                #pragma unroll
                for (int mi = 0; mi < 2; ++mi)
                    #pragma unroll
                    for (int ni = 0; ni < 4; ++ni)
                        acc1[mi][ni] = __builtin_amdgcn_mfma_f32_16x16x32_f16(aH[mi][ks * 2 + kb], bH[ni], acc1[mi][ni], 0, 0, 0);
            }
        }

        const int colbase = nt * 128 + wc * 64 + l15;
        float cn0 = cn3[colbase];
        float cn1 = cn3[colbase + 16];
        float cn2 = cn3[colbase + 32];
        float cn3v = cn3[colbase + 48];
        #pragma unroll
        for (int mi = 0; mi < 2; ++mi)
            #pragma unroll
            for (int j = 0; j < 4; ++j) {
                const int s = mi * 4 + j;
                float x0 = acc1[mi][0][j] - cn0;
                float x1 = acc1[mi][1][j] - cn1;
                float x2 = acc1[mi][2][j] - cn2;
                float x3 = acc1[mi][3][j] - cn3v;
                float mx = fmaxf(fmaxf(x0, x1), fmaxf(x2, x3));
                if (mx > v1s[s]) {          // rare: new global max
                    int nidx; float rest;
                    if (x0 == mx)      { nidx = 0; rest = fmaxf(fmaxf(x1, x2), x3); }
                    else if (x1 == mx) { nidx = 1; rest = fmaxf(fmaxf(x0, x2), x3); }
                    else if (x2 == mx) { nidx = 2; rest = fmaxf(fmaxf(x0, x1), x3); }
                    else               { nidx = 3; rest = fmaxf(fmaxf(x0, x1), x2); }
                    v2s[s] = fmaxf(v1s[s], rest);
                    v1s[s] = mx;
                    i1s[s] = colbase + nidx * 16;
                } else {
                    v2s[s] = fmaxf(v2s[s], mx);
                }
            }
    }

    #pragma unroll
    for (int s = 0; s < 8; ++s) {
        float a1 = v1s[s], a2 = v2s[s];
        int ai = i1s[s];
        #pragma unroll
        for (int m = 1; m < 16; m <<= 1) {
            float b1 = __shfl_xor(a1, m);
            float b2 = __shfl_xor(a2, m);
            int   bi = __shfl_xor(ai, m);
            float n2 = fmaxf(fminf(a1, b1), fmaxf(a2, b2));
            if (b1 > a1 || (b1 == a1 && bi < ai)) { a1 = b1; ai = bi; }
            a2 = n2;
        }
        v1s[s] = a1; v2s[s] = a2; i1s[s] = ai;
    }
    if (l15 == 0) {
        #pragma unroll
        for (int s = 0; s < 8; ++s) {
            int mi = s >> 2, j = s & 3;
            int rloc = wr * 32 + mi * 16 + lhi * 4 + j;
            mV1[rloc][wc] = v1s[s]; mV2[rloc][wc] = v2s[s];
            mI1[rloc][wc] = i1s[s];
        }
    }
    __syncthreads();
    if (tid < 64) {
        float a1 = mV1[tid][0], a2 = mV2[tid][0], b1 = mV1[tid][1], b2 = mV2[tid][1];
        int ai = mI1[tid][0], bi = mI1[tid][1];
        float n2 = fmaxf(fminf(a1, b1), fmaxf(a2, b2));
        if (b1 > a1 || (b1 == a1 && bi < ai)) { a1 = b1; ai = bi; }
        out_idx[m0 + tid] = ai;
        if (a1 - n2 < TAU) {
            int slot = atomicAdd(fs_cnt, 1);
            fs_list[slot] = m0 + tid;
        }
    }
}

// ---------------------------------------------------------------- K3b: cb transpose (f32)
__global__ __launch_bounds__(256) void vq_transpose_cb(
    const float* __restrict__ cb, float* __restrict__ cbT)
{
    __shared__ float t[64][65];
    const int j0 = blockIdx.x * 64, d0 = blockIdx.y * 64;
    const int tid = threadIdx.x;
    for (int e = tid; e < 4096; e += 256) {
        int jr = e >> 6, dc = e & 63;
        t[jr][dc] = cb[(size_t)(j0 + jr) * DDIM + d0 + dc];
    }
    __syncthreads();
    for (int e = tid; e < 4096; e += 256) {
        int dr = e >> 6, jc = e & 63;
        cbT[(size_t)(d0 + dr) * KEMB + j0 + jc] = t[jc][dr];
    }
}

// ---------------------------------------------------------------- K3c: np-exact proj for flagged rows (v2)
__global__ __launch_bounds__(256) void vq_proj_exact_rows(
    const float* __restrict__ feat, const float* __restrict__ WT,
    const float* __restrict__ bias, const int* __restrict__ fs_list,
    const int* __restrict__ fs_cnt, float* __restrict__ pf)
{
    const int d = threadIdx.x;
    int cnt = *fs_cnt;
    if (cnt > ROWS) cnt = ROWS;
    for (int base = blockIdx.x * ERB; base < cnt; base += gridDim.x * ERB) {
        const int nr = min(ERB, cnt - base);
        int rows[ERB];
        #pragma unroll
        for (int r = 0; r < ERB; ++r)
            rows[r] = fs_list[base + ((r < nr) ? r : (nr - 1))];

        float acc[ERB][4];
        #pragma unroll
        for (int r = 0; r < ERB; ++r)
            #pragma unroll
            for (int l = 0; l < 4; ++l)
                acc[r][l] = 0.0f;

        #pragma unroll 1
        for (int ch = 0; ch < IN_DIM / 16; ++ch) {
            const int ko = ch * 16;
            float wk[16];
            #pragma unroll
            for (int k = 0; k < 16; ++k)
                wk[k] = WT[(size_t)(ko + k) * DDIM + d];
            #pragma unroll
            for (int r = 0; r < ERB; ++r) {
                const float* fr = feat + (size_t)rows[r] * IN_DIM + ko;  // uniform
                float4 f3 = *(const float4*)(fr + 12);
                float4 f2 = *(const float4*)(fr + 8);
                float4 f1 = *(const float4*)(fr + 4);
                float4 f0 = *(const float4*)(fr);
                acc[r][0] = fadd(acc[r][0], fmul(f3.x, wk[12]));
                acc[r][1] = fadd(acc[r][1], fmul(f3.y, wk[13]));
                acc[r][2] = fadd(acc[r][2], fmul(f3.z, wk[14]));
                acc[r][3] = fadd(acc[r][3], fmul(f3.w, wk[15]));
                acc[r][0] = fadd(acc[r][0], fmul(f2.x, wk[8]));
                acc[r][1] = fadd(acc[r][1], fmul(f2.y, wk[9]));
                acc[r][2] = fadd(acc[r][2], fmul(f2.z, wk[10]));
                acc[r][3] = fadd(acc[r][3], fmul(f2.w, wk[11]));
                acc[r][0] = fadd(acc[r][0], fmul(f1.x, wk[4]));
                acc[r][1] = fadd(acc[r][1], fmul(f1.y, wk[5]));
                acc[r][2] = fadd(acc[r][2], fmul(f1.z, wk[6]));
                acc[r][3] = fadd(acc[r][3], fmul(f1.w, wk[7]));
                acc[r][0] = fadd(acc[r][0], fmul(f0.x, wk[0]));
                acc[r][1] = fadd(acc[r][1], fmul(f0.y, wk[1]));
                acc[r][2] = fadd(acc[r][2], fmul(f0.z, wk[2]));
                acc[r][3] = fadd(acc[r][3], fmul(f0.w, wk[3]));
            }
        }

        const float bv = bias[d];
        for (int r = 0; r < nr; ++r) {
            float h = fadd(fadd(acc[r][0], acc[r][1]), fadd(acc[r][2], acc[r][3]));
            pf[(size_t)rows[r] * DDIM + d] = fadd(h, bv);
        }
    }
}

// ---------------------------------------------------------------- K4: np-exact rescan (reg-blocked)
__global__ __launch_bounds__(256) void vq_np_rescan(
    const float* __restrict__ pf, const float* __restrict__ cbT,
    const int* __restrict__ fs_list, const int* __restrict__ fs_cnt,
    int* __restrict__ out_idx)
{
    __shared__ float prow[RSB][DDIM];
    __shared__ float As[RSB];
    __shared__ float rD[RSB][4];
    __shared__ int   rJ[RSB][4];
    const int tid = threadIdx.x;
    const int lane = tid & 63;
    const int wv = tid >> 6;
    int cnt = *fs_cnt;
    if (cnt > ROWS) cnt = ROWS;

    for (int base = blockIdx.x * RSB; base < cnt; base += gridDim.x * RSB) {
        const int nr = min(RSB, cnt - base);
        __syncthreads();
        for (int i = tid; i < nr * 64; i += 256) {
            int r = i >> 6, q = (i & 63) * 4;
            *(float4*)&prow[r][q] =
                *(const float4*)&pf[(size_t)fs_list[base + r] * DDIM + q];
        }
        __syncthreads();
        if (tid < nr) As[tid] = np_sumsq_256(prow[tid]);
        __syncthreads();

        float bD[RSB]; int bJ[RSB];
        #pragma unroll
        for (int r = 0; r < RSB; ++r) { bD[r] = __builtin_inff(); bJ[r] = 0x7fffffff; }

        for (int sw = 0; sw < 4; ++sw) {
            const int j0 = sw * 1024 + tid * 4;
            float4 acc[RSB];
            #pragma unroll
            for (int r = 0; r < RSB; ++r) acc[r] = (float4){0.f, 0.f, 0.f, 0.f};
            for (int d4 = 0; d4 < DDIM / 4; ++d4) {
                float4 pv[RSB];
                #pragma unroll
                for (int r = 0; r < RSB; ++r)
                    pv[r] = *(const float4*)&prow[r][d4 * 4];
                #pragma unroll
                for (int dd = 0; dd < 4; ++dd) {
                    float4 cv = *(const float4*)&cbT[(size_t)(d4 * 4 + dd) * KEMB + j0];
                    #pragma unroll
                    for (int r = 0; r < RSB; ++r) {
                        float p = (dd == 0) ? pv[r].x : (dd == 1) ? pv[r].y
                                 : (dd == 2) ? pv[r].z : pv[r].w;
                        acc[r].x = __fmaf_rn(p, cv.x, acc[r].x);
                        acc[r].y = __fmaf_rn(p, cv.y, acc[r].y);
                        acc[r].z = __fmaf_rn(p, cv.z, acc[r].z);
                        acc[r].w = __fmaf_rn(p, cv.w, acc[r].w);
                    }
                }
            }
            #pragma unroll
            for (int r = 0; r < RSB; ++r) {
                float A = As[r];
                float D0 = fadd(A, fmul(-2.0f, acc[r].x));
                float D1 = fadd(A, fmul(-2.0f, acc[r].y));
                float D2 = fadd(A, fmul(-2.0f, acc[r].z));
                float D3 = fadd(A, fmul(-2.0f, acc[r].w));
                if (D0 < bD[r]) { bD[r] = D0; bJ[r] = j0; }
                if (D1 < bD[r]) { bD[r] = D1; bJ[r] = j0 + 1; }
                if (D2 < bD[r]) { bD[r] = D2; bJ[r] = j0 + 2; }
                if (D3 < bD[r]) { bD[r] = D3; bJ[r] = j0 + 3; }
            }
        }

        #pragma unroll
        for (int r = 0; r < RSB; ++r) {
            float d_ = bD[r]; int j_ = bJ[r];
            #pragma unroll
            for (int m = 1; m < 64; m <<= 1) {
                float od = __shfl_xor(d_, m);
                int   oj = __shfl_xor(j_, m);
                if (od < d_ || (od == d_ && oj < j_)) { d_ = od; j_ = oj; }
            }
            if (lane == 0) { rD[r][wv] = d_; rJ[r][wv] = j_; }
        }
        __syncthreads();
        if (tid < nr) {
            float d_ = rD[tid][0]; int j_ = rJ[tid][0];
            #pragma unroll
            for (int q = 1; q < 4; ++q) {
                float od = rD[tid][q]; int oj = rJ[tid][q];
                if (od < d_ || (od == d_ && oj < j_)) { d_ = od; j_ = oj; }
            }
            out_idx[fs_list[base + tid]] = j_;
        }
    }
}

// ---------------------------------------------------------------- K5: gather + loss partials
__global__ __launch_bounds__(256) void vq_gather(
    const float* __restrict__ cb, const float* __restrict__ pf,
    const int* __restrict__ idx,
    float* __restrict__ out0, float* __restrict__ outIdxF,
    float* __restrict__ partials)
{
    const int tid = threadIdx.x;
    const int lane = tid & 63;
    const int w = tid >> 6;
    const int row = blockIdx.x * 4 + w;
    const int k = idx[row];

    float4 c = *(const float4*)&cb[(size_t)k * DDIM + lane * 4];
    float4 p = *(const float4*)&pf[(size_t)row * DDIM + lane * 4];
    float d0 = c.x - p.x, d1 = c.y - p.y, d2 = c.z - p.z, d3 = c.w - p.w;
    float s = d0 * d0 + d1 * d1 + d2 * d2 + d3 * d3;

    *(float4*)&out0[(size_t)row * DDIM + lane * 4] = c;
    if (lane == 0) outIdxF[row] = (float)k;

    #pragma unroll
    for (int off = 32; off > 0; off >>= 1) s += __shfl_down(s, off);
    __shared__ float red[4];
    if (lane == 0) red[w] = s;
    __syncthreads();
    if (tid == 0) partials[blockIdx.x] = red[0] + red[1] + red[2] + red[3];
}

// ---------------------------------------------------------------- K6: loss reduce
__global__ __launch_bounds__(256) void vq_loss(
    const float* __restrict__ partials, float* __restrict__ out_loss)
{
    const int tid = threadIdx.x;
    float s = 0.f;
    for (int i = tid; i < ROWS / 4; i += 256) s += partials[i];
    #pragma unroll
    for (int off = 32; off > 0; off >>= 1) s += __shfl_down(s, off);
    __shared__ float red[4];
    if ((tid & 63) == 0) red[tid >> 6] = s;
    __syncthreads();
    if (tid == 0)
        out_loss[0] = 1.25f * (red[0] + red[1] + red[2] + red[3]) / 8388608.0f;
}

// ---------------------------------------------------------------- launch
extern "C" void kernel_launch(void* const* d_in, const int* in_sizes, int n_in,
                              void* d_out, int out_size, void* d_ws, size_t ws_size,
                              hipStream_t stream) {
    const float* feat = (const float*)d_in[0];
    const float* Wm   = (const float*)d_in[1];
    const float* bias = (const float*)d_in[2];
    const float* cb   = (const float*)d_in[3];

    char* ws = (char*)d_ws;
    float* pf       = (float*)(ws);               // 32 MiB
    f16*   chiF     = (f16*)(ws + 33554432);      // 2 MiB  } chiF dead after argmin;
    float* cbT      = (float*)(ws + 33554432);    // 4 MiB  } cbT overlays
    float* cn3      = (float*)(ws + 37748736);    // 16 KiB
    int*   idx      = (int*)(ws + 37765120);      // 128 KiB
    float* partials = (float*)(ws + 37896192);    // 32 KiB
    int*   fs_cnt   = (int*)(ws + 37928960);      // 128 B
    int*   fs_list  = (int*)(ws + 37929088);      // 128 KiB (ends 38060160)
    float* WT       = (float*)(ws + 38076416);    // 1 MiB f32 [1024][256]
    f16*   phi      = (f16*)(ws + 39124992);      // 16 MiB f16 [32768][256]

    float* out0    = (float*)d_out;
    float* outLoss = (float*)d_out + 8388608;
    float* outIdxF = (float*)d_out + 8388609;

    hipMemsetAsync(fs_cnt, 0, 4, stream);
    vq_transpose_w<<<dim3(DDIM / 64, IN_DIM / 64), 256, 0, stream>>>(Wm, WT);
    vq_prep_codebook<<<KEMB, 256, 0, stream>>>(cb, chiF, cn3);
    vq_proj_mfma<<<dim3(ROWS / 128, DDIM / 64), 256, 0, stream>>>(feat, Wm, bias, pf, phi);
    vq_argmin<<<ROWS / 64, 256, 0, stream>>>(phi, chiF, cn3, idx, fs_cnt, fs_list);
    vq_transpose_cb<<<dim3(KEMB / 64, DDIM / 64), 256, 0, stream>>>(cb, cbT);
    vq_proj_exact_rows<<<256, 256, 0, stream>>>(feat, WT, bias, fs_list, fs_cnt, pf);
    vq_np_rescan<<<512, 256, 0, stream>>>(pf, cbT, fs_list, fs_cnt, idx);
    vq_gather<<<ROWS / 4, 256, 0, stream>>>(cb, pf, idx, out0, outIdxF, partials);
    vq_loss<<<1, 256, 0, stream>>>(partials, outLoss);
}